// Round 1
// baseline (8757.711 us; speedup 1.0000x reference)
//
#include <hip/hip_runtime.h>
#include <hip/hip_bf16.h>

typedef __hip_bfloat16 bf16;

#define B_   16
#define L_   512
#define HR   300
#define DM_  600
#define DK_  75
#define MAXA 8
#define NBU  38           // ceil(300/8) u-blocks per direction
#define LSTM_BLOCKS (2*NBU)

// ---------------------------------------------------------------- embed
__global__ __launch_bounds__(256) void k_embed(
    const int* __restrict__ tok, const int* __restrict__ pos, const int* __restrict__ post,
    const float* __restrict__ emb_w, const float* __restrict__ pos_w, const float* __restrict__ post_w,
    float* __restrict__ embs_t /* [t][b][360] */)
{
  int idx = blockIdx.x * 256 + threadIdx.x;
  if (idx >= L_ * B_ * 360) return;
  int d = idx % 360;
  int tb = idx / 360;
  int b = tb % B_, t = tb / B_;
  int seq = b * L_ + t;
  float v;
  if (d < 300)       v = emb_w[(long)tok[seq] * 300 + d];
  else if (d < 330)  v = pos_w[pos[seq] * 30 + (d - 300)];
  else               v = post_w[post[seq] * 30 + (d - 330)];
  embs_t[idx] = v;
}

// ---------------------------------------------------------------- generic tiled GEMM
// C[M,N] = alpha * A[M,K] @ (NT ? B[N,K]^T : B[K,N])  (+bias) (/rowdiv) (relu)
// batched: z -> (b1=z/nb2, b2=z%nb2), strides per pointer.
template<bool NT>
__global__ __launch_bounds__(256) void k_gemm(
    const float* __restrict__ A, int lda, long sA1, long sA2,
    const float* __restrict__ Bm, int ldb, long sB1, long sB2,
    float* __restrict__ C, bf16* __restrict__ Cbf, int ldc, long sC1, long sC2,
    const float* __restrict__ bias, const float* __restrict__ rowdiv,
    float alpha, int relu, int M, int N, int K, int nb2)
{
  __shared__ float As[16 * 68];
  __shared__ float Bs[16 * 68];
  int tid = threadIdx.x;
  int tx = tid & 15, ty = tid >> 4;
  int bx = blockIdx.x, by = blockIdx.y, z = blockIdx.z;
  int b1 = z / nb2, b2 = z - b1 * nb2;
  const float* Ab = A + b1 * sA1 + b2 * sA2;
  const float* Bb = Bm + b1 * sB1 + b2 * sB2;
  int row0 = by * 64, col0 = bx * 64;
  float acc[4][4];
#pragma unroll
  for (int i = 0; i < 4; ++i)
#pragma unroll
    for (int j = 0; j < 4; ++j) acc[i][j] = 0.f;

  int lm = tid >> 2;            // 0..63
  int kq = (tid & 3) * 4;       // 0,4,8,12
  int nn_n = tid & 63, nn_k = (tid >> 6) * 4;

  for (int k0 = 0; k0 < K; k0 += 16) {
#pragma unroll
    for (int i = 0; i < 4; ++i) {
      int kk = k0 + kq + i;
      int r = row0 + lm;
      As[(kq + i) * 68 + lm] = (r < M && kk < K) ? Ab[(long)r * lda + kk] : 0.f;
    }
    if (NT) {
#pragma unroll
      for (int i = 0; i < 4; ++i) {
        int kk = k0 + kq + i;
        int c = col0 + lm;
        Bs[(kq + i) * 68 + lm] = (c < N && kk < K) ? Bb[(long)c * ldb + kk] : 0.f;
      }
    } else {
#pragma unroll
      for (int i = 0; i < 4; ++i) {
        int kk = k0 + nn_k + i;
        int c = col0 + nn_n;
        Bs[(nn_k + i) * 68 + nn_n] = (c < N && kk < K) ? Bb[(long)kk * ldb + c] : 0.f;
      }
    }
    __syncthreads();
#pragma unroll
    for (int kk = 0; kk < 16; ++kk) {
      float4 av = *reinterpret_cast<const float4*>(&As[kk * 68 + ty * 4]);
      float4 bv = *reinterpret_cast<const float4*>(&Bs[kk * 68 + tx * 4]);
      float aa[4] = {av.x, av.y, av.z, av.w};
      float bb[4] = {bv.x, bv.y, bv.z, bv.w};
#pragma unroll
      for (int i = 0; i < 4; ++i)
#pragma unroll
        for (int j = 0; j < 4; ++j)
          acc[i][j] = fmaf(aa[i], bb[j], acc[i][j]);
    }
    __syncthreads();
  }

  float* Cb = C ? C + b1 * sC1 + b2 * sC2 : (float*)0;
  bf16*  Cf = Cbf ? Cbf + b1 * sC1 + b2 * sC2 : (bf16*)0;
#pragma unroll
  for (int i = 0; i < 4; ++i) {
    int r = row0 + ty * 4 + i;
    if (r >= M) continue;
    float dv = rowdiv ? rowdiv[(long)z * M + r] : 1.f;
#pragma unroll
    for (int j = 0; j < 4; ++j) {
      int c = col0 + tx * 4 + j;
      if (c >= N) continue;
      float v = acc[i][j] * alpha;
      if (bias) v += bias[c];
      if (rowdiv) v /= dv;
      if (relu) v = fmaxf(v, 0.f);
      if (Cf) Cf[(long)r * ldc + c] = __float2bfloat16(v);
      else    Cb[(long)r * ldc + c] = v;
    }
  }
}

// ---------------------------------------------------------------- persistent BiLSTM
// pre is pre-transposed: preT[j][t*16+b], j in [0,1200)
// hbuf: [2 buf][2 dir][k*16+b]  (k-major, 300x16)
__global__ __launch_bounds__(256) void k_lstm(
    const float* __restrict__ preT_f, const float* __restrict__ preT_b,
    const float* __restrict__ whh_f, const float* __restrict__ whh_b,
    const float* __restrict__ bih_f, const float* __restrict__ bhh_f,
    const float* __restrict__ bih_b, const float* __restrict__ bhh_b,
    float* __restrict__ hbuf, float* __restrict__ gcn,
    unsigned* __restrict__ bar, int nblocks)
{
  const int tid = threadIdx.x;
  const int dir = (blockIdx.x >= NBU) ? 1 : 0;
  const int ublk = blockIdx.x - dir * NBU;
  const int u0 = ublk * 8;
  const int uc = min(8, HR - u0);
  const float* pre = dir ? preT_b : preT_f;
  const float* whh = dir ? whh_b : whh_f;
  const float* bih = dir ? bih_b : bih_f;
  const float* bhh = dir ? bhh_b : bhh_f;

  __shared__ float h_lds[4864];        // 300*16 + pad (zeroed)
  __shared__ float part[8 * 32 * 16];  // [ks][jj][b]
  __shared__ float g_lds[32 * 16];     // [gate*8+uu][b]
  __shared__ float c_lds[8 * 16];
  __shared__ float bias_lds[32];

  const int jj = tid & 31;         // gate*8+uu
  const int ks = tid >> 5;         // 0..7
  const int gate = jj >> 3, uu = jj & 7;
  const bool jvalid = (uu < uc);
  const int jglob = gate * HR + u0 + uu;
  const int jsafe = jvalid ? jglob : 0;
  const int k0 = ks * 38;
  const int k1 = min(HR, k0 + 38);

  float wreg[38];
#pragma unroll
  for (int i = 0; i < 38; ++i) {
    int k = k0 + i;
    int kk2 = (k < HR) ? k : (HR - 1);
    float wv = whh[(long)jsafe * HR + kk2];
    wreg[i] = (jvalid && k < k1) ? wv : 0.f;
  }

  if (tid < 32) {
    int g2 = tid >> 3, u2 = tid & 7;
    int j2 = g2 * HR + u0 + u2;
    bias_lds[tid] = (u2 < uc) ? (bih[j2] + bhh[j2]) : 0.f;
  }
  for (int i = tid; i < 128; i += 256) c_lds[i] = 0.f;
  for (int i = 4800 + tid; i < 4864; i += 256) h_lds[i] = 0.f;
  __syncthreads();

#pragma unroll 1
  for (int s = 0; s < L_; ++s) {
    int tf = dir ? (L_ - 1 - s) : s;
    if (s > 0) {
      const float* hsrc = hbuf + ((s & 1) * 2 + dir) * 4800;
      for (int i = tid; i < 4800; i += 256) h_lds[i] = hsrc[i];
    }
    __syncthreads();
    if (s > 0) {
      float4 a0 = {0,0,0,0}, a1 = {0,0,0,0}, a2 = {0,0,0,0}, a3 = {0,0,0,0};
#pragma unroll
      for (int i = 0; i < 38; ++i) {
        int k = k0 + i;
        float w = wreg[i];
        const float4* hp = reinterpret_cast<const float4*>(h_lds + k * 16);
        float4 h0 = hp[0], h1 = hp[1], h2 = hp[2], h3 = hp[3];
        a0.x = fmaf(w, h0.x, a0.x); a0.y = fmaf(w, h0.y, a0.y); a0.z = fmaf(w, h0.z, a0.z); a0.w = fmaf(w, h0.w, a0.w);
        a1.x = fmaf(w, h1.x, a1.x); a1.y = fmaf(w, h1.y, a1.y); a1.z = fmaf(w, h1.z, a1.z); a1.w = fmaf(w, h1.w, a1.w);
        a2.x = fmaf(w, h2.x, a2.x); a2.y = fmaf(w, h2.y, a2.y); a2.z = fmaf(w, h2.z, a2.z); a2.w = fmaf(w, h2.w, a2.w);
        a3.x = fmaf(w, h3.x, a3.x); a3.y = fmaf(w, h3.y, a3.y); a3.z = fmaf(w, h3.z, a3.z); a3.w = fmaf(w, h3.w, a3.w);
      }
      float4* pp = reinterpret_cast<float4*>(part + (ks * 32 + jj) * 16);
      pp[0] = a0; pp[1] = a1; pp[2] = a2; pp[3] = a3;
    }
    __syncthreads();
    // reduce partials + pre + bias -> gates
    for (int g = tid; g < 512; g += 256) {
      int j = g >> 4, b = g & 15;
      float sum = 0.f;
      if (s > 0) {
#pragma unroll
        for (int q = 0; q < 8; ++q) sum += part[(q * 32 + j) * 16 + b];
      }
      int gg2 = j >> 3, uu2 = j & 7;
      float pv = 0.f;
      if (uu2 < uc) pv = pre[(long)(gg2 * HR + u0 + uu2) * 8192 + tf * 16 + b];
      g_lds[j * 16 + b] = pv + bias_lds[j] + sum;
    }
    __syncthreads();
    if (tid < 128) {
      int u2 = tid >> 4, b = tid & 15;
      if (u2 < uc) {
        float gi = g_lds[(0 * 8 + u2) * 16 + b];
        float gf = g_lds[(1 * 8 + u2) * 16 + b];
        float gg = g_lds[(2 * 8 + u2) * 16 + b];
        float go = g_lds[(3 * 8 + u2) * 16 + b];
        float si = 1.f / (1.f + __expf(-gi));
        float sf = 1.f / (1.f + __expf(-gf));
        float so = 1.f / (1.f + __expf(-go));
        float tg = tanhf(gg);
        float c = sf * c_lds[tid] + si * tg;
        c_lds[tid] = c;
        float h = so * tanhf(c);
        hbuf[(((s + 1) & 1) * 2 + dir) * 4800 + (u0 + u2) * 16 + b] = h;
        gcn[((long)b * L_ + tf) * DM_ + dir * HR + u0 + u2] = h;
      }
    }
    __syncthreads();
    if (tid == 0) {
      __threadfence();
      unsigned a = __hip_atomic_fetch_add(bar, 1u, __ATOMIC_ACQ_REL, __HIP_MEMORY_SCOPE_AGENT);
      unsigned target = (a / (unsigned)nblocks + 1u) * (unsigned)nblocks;
      while (__hip_atomic_load(bar, __ATOMIC_ACQUIRE, __HIP_MEMORY_SCOPE_AGENT) < target) {
        __builtin_amdgcn_s_sleep(2);
      }
      __threadfence();
    }
    __syncthreads();
  }
}

// ---------------------------------------------------------------- small aspect kernels
__global__ void k_asplist(const float* __restrict__ asp_mask, int* __restrict__ apos, int* __restrict__ acnt)
{
  int b = threadIdx.x;
  if (b >= B_) return;
  int c = 0;
  for (int l = 0; l < L_; ++l)
    if (asp_mask[b * L_ + l] > 0.f) { if (c < MAXA) apos[b * MAXA + c] = l; ++c; }
  acnt[b] = (c < MAXA) ? c : MAXA;
}

__global__ void k_t0(const float* __restrict__ bd, const float* __restrict__ wm, float* __restrict__ t0)
{
  int i = blockIdx.x * 256 + threadIdx.x;
  if (i >= 8 * DK_) return;
  int h = i / DK_, e = i % DK_;
  float s = 0.f;
  for (int d = 0; d < DK_; ++d) s += bd[d] * wm[(h * DK_ + d) * DK_ + e];
  t0[i] = s;
}

__global__ void k_aspd(const float* __restrict__ gcn, const float* __restrict__ asp_mask,
                       const int* __restrict__ apos, const int* __restrict__ acnt,
                       const float* __restrict__ wd, const float* __restrict__ bd, float* __restrict__ aspd)
{
  int i = blockIdx.x * 256 + threadIdx.x;
  if (i >= B_ * MAXA * DK_) return;
  int d = i % DK_;
  int ba = i / DK_;
  int a = ba % MAXA, b = ba / MAXA;
  if (a >= acnt[b]) { aspd[i] = 0.f; return; }
  int p = apos[b * MAXA + a];
  float mv = asp_mask[b * L_ + p];
  const float* row = gcn + ((long)b * L_ + p) * DM_;
  float s = 0.f;
  for (int k = 0; k < DM_; ++k) s += row[k] * wd[d * DM_ + k];
  aspd[i] = s * mv + bd[d];
}

__global__ void k_tasp(const float* __restrict__ aspd, const int* __restrict__ acnt,
                       const float* __restrict__ wm, float* __restrict__ tasp)
{
  int i = blockIdx.x * 256 + threadIdx.x;
  if (i >= B_ * 8 * MAXA * DK_) return;
  int e = i % DK_;
  int t3 = i / DK_;
  int a = t3 % MAXA;
  int t4 = t3 / MAXA;
  int h = t4 % 8, b = t4 / 8;
  if (a >= acnt[b]) { tasp[i] = 0.f; return; }
  const float* ar = aspd + (b * MAXA + a) * DK_;
  float s = 0.f;
  for (int d = 0; d < DK_; ++d) s += ar[d] * wm[(h * DK_ + d) * DK_ + e];
  tasp[i] = s;
}

__global__ void k_avg(const float* __restrict__ k_lin, const float* __restrict__ t0,
                      const float* __restrict__ tasp, const int* __restrict__ acnt,
                      const float* __restrict__ bias_m, float* __restrict__ s0, float* __restrict__ avg)
{
  int i = blockIdx.x * 256 + threadIdx.x;
  if (i >= B_ * 8 * L_) return;
  int m = i % L_;
  int bh = i / L_;
  int h = bh % 8, b = bh / 8;
  const float* kr = k_lin + ((long)b * L_ + m) * DM_ + h * DK_;
  float bm = bias_m[0];
  const float* t0r = t0 + h * DK_;
  float d0 = 0.f;
  for (int e = 0; e < DK_; ++e) d0 += t0r[e] * kr[e];
  float sv = tanhf(d0 + bm);
  int cnt = acnt[b];
  float acc = (float)(L_ - cnt) * sv;
  for (int a = 0; a < cnt; ++a) {
    const float* tr = tasp + (((b * 8 + h) * MAXA) + a) * DK_;
    float dd = 0.f;
    for (int e = 0; e < DK_; ++e) dd += tr[e] * kr[e];
    acc += tanhf(dd + bm);
  }
  s0[i] = sv;
  avg[i] = acc * (1.f / (float)L_);
}

__global__ void k_bar(const float* __restrict__ s0, const float* __restrict__ avg,
                      float* __restrict__ s0bar, float* __restrict__ avbar)
{
  int i = blockIdx.x * 256 + threadIdx.x;
  if (i >= B_ * L_) return;
  int m = i % L_, b = i / L_;
  float sa = 0.f, aa = 0.f;
  for (int h = 0; h < 8; ++h) { sa += s0[(b * 8 + h) * L_ + m]; aa += avg[(b * 8 + h) * L_ + m]; }
  s0bar[i] = sa * 0.125f;
  avbar[i] = aa * 0.125f;
}

// adj_ag + denom_ag ; one block per (b,l)
__global__ __launch_bounds__(256) void k_adjag(
    const float* __restrict__ asp_mask, const float* __restrict__ adjr,
    const float* __restrict__ s0bar, const float* __restrict__ avbar,
    float* __restrict__ adjag, float* __restrict__ denag)
{
  int bl = blockIdx.x;
  int b = bl >> 9, l = bl & 511;
  bool rA = asp_mask[b * L_ + l] > 0.f;
  float avl = avbar[b * L_ + l];
  float lsum = 0.f;
  for (int q = 0; q < 2; ++q) {
    int m = threadIdx.x + q * 256;
    bool cA = asp_mask[b * L_ + m] > 0.f;
    float asv;
    if (cA && (!rA || m > l)) asv = avl;
    else if (rA)              asv = avbar[b * L_ + m];
    else                      asv = s0bar[b * L_ + m];
    float r = (asv > 0.9f) ? 1.f : __expf(0.8f * adjr[((long)b * L_ + l) * L_ + m]);
    float v = r * asv;
    adjag[((long)b * L_ + l) * L_ + m] = v;
    lsum += v;
  }
  __shared__ float red[256];
  red[threadIdx.x] = lsum;
  __syncthreads();
  for (int st = 128; st > 0; st >>= 1) {
    if (threadIdx.x < st) red[threadIdx.x] += red[threadIdx.x + st];
    __syncthreads();
  }
  if (threadIdx.x == 0) denag[bl] = red[0] + 1.f;
}

// per-row (b,h,l) max & sumexp over bf16 scores; one wave per row
__global__ __launch_bounds__(256) void k_stats(
    const bf16* __restrict__ sc, const int* __restrict__ tok,
    float* __restrict__ mx, float* __restrict__ sm)
{
  int row = blockIdx.x * 4 + (threadIdx.x >> 6);
  int lane = threadIdx.x & 63;
  if (row >= B_ * 8 * L_) return;
  int b = row >> 12;
  const bf16* p = sc + (long)row * L_;
  const int* tkb = tok + b * L_;
  float v[8];
#pragma unroll
  for (int i = 0; i < 8; ++i) {
    int m = lane * 8 + i;
    float s = __bfloat162float(p[m]);
    v[i] = (tkb[m] != 0) ? s : -1e9f;
  }
  float mxl = v[0];
#pragma unroll
  for (int i = 1; i < 8; ++i) mxl = fmaxf(mxl, v[i]);
  for (int off = 32; off > 0; off >>= 1) mxl = fmaxf(mxl, __shfl_xor(mxl, off));
  float s = 0.f;
#pragma unroll
  for (int i = 0; i < 8; ++i) s += __expf(v[i] - mxl);
  for (int off = 32; off > 0; off >>= 1) s += __shfl_xor(s, off);
  if (lane == 0) { mx[row] = mxl; sm[row] = s; }
}

// adj_s = head-mean softmax, diag=1, row tok-mask, + denom_s; block per (b,l)
__global__ __launch_bounds__(256) void k_adjs(
    const bf16* __restrict__ sc, const int* __restrict__ tok,
    const float* __restrict__ mx, const float* __restrict__ sm,
    float* __restrict__ adjs, float* __restrict__ dens)
{
  int bl = blockIdx.x;
  int b = bl >> 9, l = bl & 511;
  float acc0 = 0.f, acc1 = 0.f;
  for (int h = 0; h < 8; ++h) {
    int row = (b * 8 + h) * L_ + l;
    float mxv = mx[row];
    float inv = 1.f / sm[row];
    const bf16* p = sc + (long)row * L_;
    {
      int m = threadIdx.x;
      float s = __bfloat162float(p[m]);
      s = (tok[b * L_ + m] != 0) ? s : -1e9f;
      acc0 += __expf(s - mxv) * inv;
    }
    {
      int m = threadIdx.x + 256;
      float s = __bfloat162float(p[m]);
      s = (tok[b * L_ + m] != 0) ? s : -1e9f;
      acc1 += __expf(s - mxv) * inv;
    }
  }
  float rmask = (tok[b * L_ + l] != 0) ? 1.f : 0.f;
  float lsum = 0.f;
  {
    int m = threadIdx.x;
    float v = acc0 * 0.125f;
    v = (m == l) ? 1.f : v;
    v *= rmask;
    adjs[(long)bl * L_ + m] = v;
    lsum += v;
  }
  {
    int m = threadIdx.x + 256;
    float v = acc1 * 0.125f;
    v = (m == l) ? 1.f : v;
    v *= rmask;
    adjs[(long)bl * L_ + m] = v;
    lsum += v;
  }
  __shared__ float red[256];
  red[threadIdx.x] = lsum;
  __syncthreads();
  for (int st = 128; st > 0; st >>= 1) {
    if (threadIdx.x < st) red[threadIdx.x] += red[threadIdx.x + st];
    __syncthreads();
  }
  if (threadIdx.x == 0) dens[bl] = red[0] + 1.f;
}

// in-place row softmax (rows of length 512)
__global__ __launch_bounds__(256) void k_softmax(float* __restrict__ X)
{
  long row = blockIdx.x;
  float* p = X + row * L_;
  int tid = threadIdx.x;
  float a = p[tid], b = p[tid + 256];
  __shared__ float red[256];
  red[tid] = fmaxf(a, b);
  __syncthreads();
  for (int st = 128; st > 0; st >>= 1) {
    if (tid < st) red[tid] = fmaxf(red[tid], red[tid + st]);
    __syncthreads();
  }
  float mxv = red[0];
  __syncthreads();
  float ea = __expf(a - mxv), eb = __expf(b - mxv);
  red[tid] = ea + eb;
  __syncthreads();
  for (int st = 128; st > 0; st >>= 1) {
    if (tid < st) red[tid] += red[tid + st];
    __syncthreads();
  }
  float inv = 1.f / red[0];
  p[tid] = ea * inv;
  p[tid + 256] = eb * inv;
}

// ---------------------------------------------------------------- host side
static void gemm(hipStream_t st, bool nt,
                 const float* A, int lda, long sA1, long sA2,
                 const float* Bm, int ldb, long sB1, long sB2,
                 float* C, bf16* Cbf, int ldc, long sC1, long sC2,
                 const float* bias, const float* rowdiv,
                 float alpha, int relu, int M, int N, int K, int nb1, int nb2)
{
  dim3 g((N + 63) / 64, (M + 63) / 64, nb1 * nb2);
  if (nt)
    k_gemm<true><<<g, 256, 0, st>>>(A, lda, sA1, sA2, Bm, ldb, sB1, sB2, C, Cbf, ldc, sC1, sC2,
                                    bias, rowdiv, alpha, relu, M, N, K, nb2);
  else
    k_gemm<false><<<g, 256, 0, st>>>(A, lda, sA1, sA2, Bm, ldb, sB1, sB2, C, Cbf, ldc, sC1, sC2,
                                     bias, rowdiv, alpha, relu, M, N, K, nb2);
}

extern "C" void kernel_launch(void* const* d_in, const int* in_sizes, int n_in,
                              void* d_out, int out_size, void* d_ws, size_t ws_size,
                              hipStream_t stream)
{
  const int*   tok     = (const int*)d_in[0];
  const int*   pos     = (const int*)d_in[1];
  const int*   post    = (const int*)d_in[2];
  const float* asp_mask= (const float*)d_in[3];
  const float* adjr    = (const float*)d_in[5];
  const float* emb_w   = (const float*)d_in[6];
  const float* pos_w   = (const float*)d_in[7];
  const float* post_w  = (const float*)d_in[8];
  const float* w_ih_f  = (const float*)d_in[9];
  const float* w_hh_f  = (const float*)d_in[10];
  const float* b_ih_f  = (const float*)d_in[11];
  const float* b_hh_f  = (const float*)d_in[12];
  const float* w_ih_b  = (const float*)d_in[13];
  const float* w_hh_b  = (const float*)d_in[14];
  const float* b_ih_b  = (const float*)d_in[15];
  const float* b_hh_b  = (const float*)d_in[16];
  const float* wq      = (const float*)d_in[17];
  const float* bq      = (const float*)d_in[18];
  const float* wk      = (const float*)d_in[19];
  const float* bk      = (const float*)d_in[20];
  const float* wd      = (const float*)d_in[21];
  const float* bd      = (const float*)d_in[22];
  const float* wm      = (const float*)d_in[23];
  const float* bias_m  = (const float*)d_in[24];
  const float* wa0     = (const float*)d_in[25];
  const float* ba0     = (const float*)d_in[26];
  const float* wa1     = (const float*)d_in[27];
  const float* ba1     = (const float*)d_in[28];
  const float* ws0     = (const float*)d_in[29];
  const float* bs0     = (const float*)d_in[30];
  const float* ws1     = (const float*)d_in[31];
  const float* bs1     = (const float*)d_in[32];
  const float* aff1    = (const float*)d_in[33];
  const float* aff2    = (const float*)d_in[34];
  float* out = (float*)d_out;
  float* W = (float*)d_ws;

  // ---- workspace layout (float units, 256B aligned) ----
  size_t off = 0;
  auto alloc = [&](size_t n) { size_t o = off; off += (n + 63) & ~(size_t)63; return o; };
  size_t o_cnt   = alloc(64);
  size_t o_hbuf  = alloc(2 * 2 * 4800);
  size_t o_gcn   = alloc((size_t)8192 * DM_);
  size_t o_q     = alloc((size_t)8192 * DM_);
  size_t o_k     = alloc((size_t)8192 * DM_);
  size_t o_adjs  = alloc((size_t)B_ * L_ * L_);
  size_t o_dens  = alloc(8192);
  size_t o_adjag = alloc((size_t)B_ * L_ * L_);
  size_t o_denag = alloc(8192);
  size_t o_t0    = alloc(600);
  size_t o_apos  = alloc(B_ * MAXA);
  size_t o_acnt  = alloc(64);
  size_t o_aspd  = alloc(B_ * MAXA * DK_);
  size_t o_tasp  = alloc(B_ * 8 * MAXA * DK_);
  size_t o_s0    = alloc(B_ * 8 * L_);
  size_t o_avg   = alloc(B_ * 8 * L_);
  size_t o_s0bar = alloc(B_ * L_);
  size_t o_avbar = alloc(B_ * L_);
  size_t o_mx    = alloc(B_ * 8 * L_);
  size_t o_sm    = alloc(B_ * 8 * L_);
  size_t o_oag1  = alloc((size_t)8192 * 300);
  size_t o_os1   = alloc((size_t)8192 * 300);
  size_t o_big   = alloc(22609920);   // union region
  // union A: embs(2,949,120) + preT_f(9,830,400) + preT_b(9,830,400)
  size_t o_embs = o_big;
  size_t o_pref = o_big + 2949120;
  size_t o_preb = o_pref + 9830400;
  // union B: scores bf16 (33,554,432 bf16 = 16,777,216 float slots)
  size_t o_sc   = o_big;
  // union C: GCN temps
  size_t o_tmp  = o_big;
  size_t o_gag  = o_big + 4915200;
  size_t o_gs   = o_gag + 2457600;
  size_t o_h1   = o_gs  + 2457600;
  size_t o_a1m  = o_h1  + 2457600;
  size_t o_a2m  = o_a1m + 4194304;

  if (ws_size < off * sizeof(float)) {
    // workspace too small: write sentinel so the failure is distinguishable
    hipMemsetAsync(d_out, 0x7F, (size_t)out_size * sizeof(float), stream);
    return;
  }

  // barrier counter -> 0 (replay-safe; monotonic barrier needs a 0 start each launch)
  hipMemsetAsync((void*)(W + o_cnt), 0, 256, stream);

  // 1) embeddings (to [t][b][360])
  k_embed<<<(L_ * B_ * 360 + 255) / 256, 256, 0, stream>>>(tok, pos, post, emb_w, pos_w, post_w, W + o_embs);

  // 2) pre-GEMMs, transposed output: preT[j][t*16+b] = w_ih[j] . embs[(t,b)]
  gemm(stream, true, w_ih_f, 360, 0, 0, W + o_embs, 360, 0, 0,
       W + o_pref, nullptr, 8192, 0, 0, nullptr, nullptr, 1.f, 0, 1200, 8192, 360, 1, 1);
  gemm(stream, true, w_ih_b, 360, 0, 0, W + o_embs, 360, 0, 0,
       W + o_preb, nullptr, 8192, 0, 0, nullptr, nullptr, 1.f, 0, 1200, 8192, 360, 1, 1);

  // 3) persistent BiLSTM -> gcn_inputs [b][t][600]
  k_lstm<<<LSTM_BLOCKS, 256, 0, stream>>>(W + o_pref, W + o_preb, w_hh_f, w_hh_b,
                                          b_ih_f, b_hh_f, b_ih_b, b_hh_b,
                                          W + o_hbuf, W + o_gcn,
                                          (unsigned*)(W + o_cnt), LSTM_BLOCKS);

  // 4) q/k projections
  gemm(stream, true, W + o_gcn, DM_, 0, 0, wq, DM_, 0, 0,
       W + o_q, nullptr, DM_, 0, 0, bq, nullptr, 1.f, 0, 8192, DM_, DM_, 1, 1);
  gemm(stream, true, W + o_gcn, DM_, 0, 0, wk, DM_, 0, 0,
       W + o_k, nullptr, DM_, 0, 0, bk, nullptr, 1.f, 0, 8192, DM_, DM_, 1, 1);

  // 5) aspect structure
  k_asplist<<<1, 64, 0, stream>>>(asp_mask, (int*)(W + o_apos), (int*)(W + o_acnt));
  k_t0<<<(600 + 255) / 256, 256, 0, stream>>>(bd, wm, W + o_t0);
  k_aspd<<<(B_ * MAXA * DK_ + 255) / 256, 256, 0, stream>>>(W + o_gcn, asp_mask,
      (const int*)(W + o_apos), (const int*)(W + o_acnt), wd, bd, W + o_aspd);
  k_tasp<<<(B_ * 8 * MAXA * DK_ + 255) / 256, 256, 0, stream>>>(W + o_aspd,
      (const int*)(W + o_acnt), wm, W + o_tasp);
  k_avg<<<(B_ * 8 * L_ + 255) / 256, 256, 0, stream>>>(W + o_k, W + o_t0, W + o_tasp,
      (const int*)(W + o_acnt), bias_m, W + o_s0, W + o_avg);
  k_bar<<<(B_ * L_ + 255) / 256, 256, 0, stream>>>(W + o_s0, W + o_avg, W + o_s0bar, W + o_avbar);

  // 6) scores = q.k^T/sqrt(75) (bf16, batched over (b,h)) -> stats -> adj_s ; adj_ag
  gemm(stream, true, W + o_q, DM_, (long)L_ * DM_, DK_, W + o_k, DM_, (long)L_ * DM_, DK_,
       nullptr, (bf16*)(W + o_sc), L_, (long)8 * L_ * L_, (long)L_ * L_,
       nullptr, nullptr, 0.1154700538f, 0, L_, L_, DK_, B_, 8);
  k_stats<<<(B_ * 8 * L_) / 4, 256, 0, stream>>>((const bf16*)(W + o_sc), tok, W + o_mx, W + o_sm);
  k_adjs<<<B_ * L_, 256, 0, stream>>>((const bf16*)(W + o_sc), tok, W + o_mx, W + o_sm,
                                      W + o_adjs, W + o_dens);
  k_adjag<<<B_ * L_, 256, 0, stream>>>(asp_mask, adjr, W + o_s0bar, W + o_avbar,
                                       W + o_adjag, W + o_denag);

  // 7) two GCN layers
  const float* waL[2] = {wa0, wa1};
  const float* baL[2] = {ba0, ba1};
  const float* wsL[2] = {ws0, ws1};
  const float* bsL[2] = {bs0, bs1};
  const float* inAg = W + o_gcn;
  const float* inS  = W + o_gcn;
  int D = DM_;
  for (int layer = 0; layer < 2; ++layer) {
    // g_ag = relu((adj_ag @ inAg @ wa^T + ba)/denom_ag)
    gemm(stream, false, W + o_adjag, L_, (long)L_ * L_, 0, inAg, D, (long)L_ * D, 0,
         W + o_tmp, nullptr, D, (long)L_ * D, 0, nullptr, nullptr, 1.f, 0, L_, D, L_, B_, 1);
    gemm(stream, true, W + o_tmp, D, 0, 0, waL[layer], D, 0, 0,
         W + o_gag, nullptr, 300, 0, 0, baL[layer], W + o_denag, 1.f, 1, 8192, 300, D, 1, 1);
    // g_s
    gemm(stream, false, W + o_adjs, L_, (long)L_ * L_, 0, inS, D, (long)L_ * D, 0,
         W + o_tmp, nullptr, D, (long)L_ * D, 0, nullptr, nullptr, 1.f, 0, L_, D, L_, B_, 1);
    gemm(stream, true, W + o_tmp, D, 0, 0, wsL[layer], D, 0, 0,
         W + o_gs, nullptr, 300, 0, 0, bsL[layer], W + o_dens, 1.f, 1, 8192, 300, D, 1, 1);
    // A1 = softmax((g_ag @ aff1) @ g_s^T)
    gemm(stream, false, W + o_gag, 300, 0, 0, aff1, 300, 0, 0,
         W + o_h1, nullptr, 300, 0, 0, nullptr, nullptr, 1.f, 0, 8192, 300, 300, 1, 1);
    gemm(stream, true, W + o_h1, 300, (long)L_ * 300, 0, W + o_gs, 300, (long)L_ * 300, 0,
         W + o_a1m, nullptr, L_, (long)L_ * L_, 0, nullptr, nullptr, 1.f, 0, L_, L_, 300, B_, 1);
    k_softmax<<<B_ * L_, 256, 0, stream>>>(W + o_a1m);
    // A2 = softmax((g_s @ aff2) @ g_ag^T)
    gemm(stream, false, W + o_gs, 300, 0, 0, aff2, 300, 0, 0,
         W + o_h1, nullptr, 300, 0, 0, nullptr, nullptr, 1.f, 0, 8192, 300, 300, 1, 1);
    gemm(stream, true, W + o_h1, 300, (long)L_ * 300, 0, W + o_gag, 300, (long)L_ * 300, 0,
         W + o_a2m, nullptr, L_, (long)L_ * L_, 0, nullptr, nullptr, 1.f, 0, L_, L_, 300, B_, 1);
    k_softmax<<<B_ * L_, 256, 0, stream>>>(W + o_a2m);
    // out_ag = A1 @ g_s ; out_s = A2 @ g_ag
    float* dstAg; float* dstS; int ldcO; long sCO;
    if (layer == 0) { dstAg = W + o_oag1; dstS = W + o_os1; ldcO = 300; sCO = (long)L_ * 300; }
    else            { dstAg = out;        dstS = out + 300; ldcO = 600; sCO = (long)L_ * 600; }
    gemm(stream, false, W + o_a1m, L_, (long)L_ * L_, 0, W + o_gs, 300, (long)L_ * 300, 0,
         dstAg, nullptr, ldcO, sCO, 0, nullptr, nullptr, 1.f, 0, L_, 300, L_, B_, 1);
    gemm(stream, false, W + o_a2m, L_, (long)L_ * L_, 0, W + o_gag, 300, (long)L_ * 300, 0,
         dstS, nullptr, ldcO, sCO, 0, nullptr, nullptr, 1.f, 0, L_, 300, L_, B_, 1);
    inAg = W + o_oag1;
    inS  = W + o_os1;
    D = 300;
  }
}